// Round 5
// baseline (154.601 us; speedup 1.0000x reference)
//
#include <hip/hip_runtime.h>

#define HID 16
#define TLEN 1024

typedef float v4f __attribute__((ext_vector_type(4)));

__device__ __forceinline__ float fast_exp2(float a) { return __builtin_amdgcn_exp2f(a); }
__device__ __forceinline__ float fast_rcp(float a)  { return __builtin_amdgcn_rcpf(a); }

// tanh(a) = 1 - 2/(exp2(2a*log2e)+1)  (epilogue only, unscaled input)
__device__ __forceinline__ float fast_tanh(float a) {
    return __builtin_fmaf(-2.0f, fast_rcp(1.0f + fast_exp2(a * 2.8853900817779268f)), 1.0f);
}

// One v_fmac_f32_dpp per (gate, rotation): acc += h[(lane-R)&15] * w.
// DPP row_ror:R verified on HW (R4): dst[i] = src[(i-R)&15] within 16-lane rows.
#define ROT3(Rs) \
    "v_fmac_f32_dpp %[ar], %[h], %[wr" Rs "] row_ror:" Rs " row_mask:0xf bank_mask:0xf\n\t" \
    "v_fmac_f32_dpp %[az], %[h], %[wz" Rs "] row_ror:" Rs " row_mask:0xf bank_mask:0xf\n\t" \
    "v_fmac_f32_dpp %[an], %[h], %[wn" Rs "] row_ror:" Rs " row_mask:0xf bank_mask:0xf\n\t"

// One lane per (sequence, hidden unit j). 64-thread blocks = 1 wave = 4 sequences.
// grid = B/4 = 1024 waves -> 1 wave per SIMD across 256 CUs (occupancy is
// structurally capped; all gains must come from per-step instruction count).
__global__ __launch_bounds__(64, 1) void gru_fused_kernel(
    const float* __restrict__ x,     // [B, T, 1]
    const float* __restrict__ W_ih,  // [48, 1]
    const float* __restrict__ W_hh,  // [48, 16]
    const float* __restrict__ b_ih,  // [48]
    const float* __restrict__ b_hh,  // [48]
    const float* __restrict__ W_fc,  // [5, 16]
    const float* __restrict__ b_fc,  // [5]
    float* __restrict__ out)         // [B, 5]
{
    const int lane = threadIdx.x;      // 0..63
    const int j    = lane & 15;        // hidden unit
    const int g    = lane >> 4;        // sequence-within-wave (0..3)
    const int b    = blockIdx.x * 4 + g;

    const float NEG_LOG2E = -1.4426950408889634f;  // sigmoid: rcp(1+exp2(-a*log2e))
    const float TWO_LOG2E =  2.8853900817779268f;  // tanh:    1-2*rcp(1+exp2(2a*log2e))

    // Per-lane weights ordered by rotation r: w[r] = W[j][(j-r)&15], pre-scaled
    // by the exp2 activation constants (no mul in front of v_exp_f32).
    float wr[16], wz[16], wn[16];
    #pragma unroll
    for (int r = 0; r < 16; ++r) {
        const int k = (j - r) & 15;
        wr[r] = W_hh[(j     ) * HID + k] * NEG_LOG2E;
        wz[r] = W_hh[(j + 16) * HID + k] * NEG_LOG2E;
        wn[r] = W_hh[(j + 32) * HID + k] * TWO_LOG2E;
    }
    const float wih_r = W_ih[j]      * NEG_LOG2E;
    const float wih_z = W_ih[j + 16] * NEG_LOG2E;
    const float wih_n = W_ih[j + 32] * TWO_LOG2E;
    const float br  = (b_ih[j]      + b_hh[j])      * NEG_LOG2E;
    const float bz  = (b_ih[j + 16] + b_hh[j + 16]) * NEG_LOG2E;
    const float bnx = b_ih[j + 32] * TWO_LOG2E;    // input-side n bias
    const float bnh = b_hh[j + 32] * TWO_LOG2E;    // hidden-side n bias (inside r*)

    const float* __restrict__ xb = x + (size_t)b * TLEN;

    float h = 0.0f;
    // current chunk's 16 x values, full copy per lane (same cachelines per group)
    v4f xc0 = *(const v4f*)(xb +  0);
    v4f xc1 = *(const v4f*)(xb +  4);
    v4f xc2 = *(const v4f*)(xb +  8);
    v4f xc3 = *(const v4f*)(xb + 12);

    for (int t0 = 0; t0 < TLEN; t0 += 16) {
        // prefetch next chunk (independent of the recurrence)
        v4f xn0 = {0,0,0,0}, xn1 = {0,0,0,0}, xn2 = {0,0,0,0}, xn3 = {0,0,0,0};
        if (t0 + 16 < TLEN) {
            xn0 = *(const v4f*)(xb + t0 + 16);
            xn1 = *(const v4f*)(xb + t0 + 20);
            xn2 = *(const v4f*)(xb + t0 + 24);
            xn3 = *(const v4f*)(xb + t0 + 28);
        }

        const v4f xcs[4] = { xc0, xc1, xc2, xc3 };
        #pragma unroll
        for (int i = 0; i < 16; ++i) {
            const float xt = xcs[i >> 2][i & 3];   // compile-time indices

            // accumulator init: input terms + r=0 contribution (plain VALU;
            // these also provide >=2 wait-states between h's write and the
            // first DPP read of h below)
            float ar = __builtin_fmaf(xt, wih_r, br);
            float az = __builtin_fmaf(xt, wih_z, bz);
            const float nx = __builtin_fmaf(xt, wih_n, bnx);
            float an = bnh;
            ar = __builtin_fmaf(h, wr[0], ar);
            az = __builtin_fmaf(h, wz[0], az);
            an = __builtin_fmaf(h, wn[0], an);

            // ---- fused gather+matvec: 45 x v_fmac_f32_dpp, 3 round-robin
            //      chains (6-cy same-acc spacing > fma latency) ----
            asm ("s_nop 1\n\t"                 // VALU-write -> DPP-read hazard on h
                 ROT3("1") ROT3("2") ROT3("3") ROT3("4")
                 ROT3("5") ROT3("6") ROT3("7") ROT3("8")
                 : [ar]"+v"(ar), [az]"+v"(az), [an]"+v"(an)
                 : [h]"v"(h),
                   [wr1]"v"(wr[1]), [wz1]"v"(wz[1]), [wn1]"v"(wn[1]),
                   [wr2]"v"(wr[2]), [wz2]"v"(wz[2]), [wn2]"v"(wn[2]),
                   [wr3]"v"(wr[3]), [wz3]"v"(wz[3]), [wn3]"v"(wn[3]),
                   [wr4]"v"(wr[4]), [wz4]"v"(wz[4]), [wn4]"v"(wn[4]),
                   [wr5]"v"(wr[5]), [wz5]"v"(wz[5]), [wn5]"v"(wn[5]),
                   [wr6]"v"(wr[6]), [wz6]"v"(wz[6]), [wn6]"v"(wn[6]),
                   [wr7]"v"(wr[7]), [wz7]"v"(wz[7]), [wn7]"v"(wn[7]),
                   [wr8]"v"(wr[8]), [wz8]"v"(wz[8]), [wn8]"v"(wn[8]));
            asm (ROT3("9")  ROT3("10") ROT3("11") ROT3("12")
                 ROT3("13") ROT3("14") ROT3("15")
                 : [ar]"+v"(ar), [az]"+v"(az), [an]"+v"(an)
                 : [h]"v"(h),
                   [wr9]"v"(wr[9]),   [wz9]"v"(wz[9]),   [wn9]"v"(wn[9]),
                   [wr10]"v"(wr[10]), [wz10]"v"(wz[10]), [wn10]"v"(wn[10]),
                   [wr11]"v"(wr[11]), [wz11]"v"(wz[11]), [wn11]"v"(wn[11]),
                   [wr12]"v"(wr[12]), [wz12]"v"(wz[12]), [wn12]"v"(wn[12]),
                   [wr13]"v"(wr[13]), [wz13]"v"(wz[13]), [wn13]"v"(wn[13]),
                   [wr14]"v"(wr[14]), [wz14]"v"(wz[14]), [wn14]"v"(wn[14]),
                   [wr15]"v"(wr[15]), [wz15]"v"(wz[15]), [wn15]"v"(wn[15]));

            // activations (weights pre-scaled: no mul before exp2)
            const float r_ = fast_rcp(1.0f + fast_exp2(ar));
            const float z_ = fast_rcp(1.0f + fast_exp2(az));
            const float s_ = __builtin_fmaf(r_, an, nx);
            const float n_ = __builtin_fmaf(-2.0f, fast_rcp(1.0f + fast_exp2(s_)), 1.0f);

            // h = (1-z)*n + z*h
            h = __builtin_fmaf(z_, h - n_, n_);
        }

        xc0 = xn0; xc1 = xn1; xc2 = xn2; xc3 = xn3;
    }

    // --- epilogue: out[b, c] = sum_j tanh(h_j) * W_fc[c, j] + b_fc[c] ---
    __shared__ float th_s[64];
    th_s[lane] = fast_tanh(h);
    __syncthreads();

    if (j < 5) {
        float acc = b_fc[j];
        #pragma unroll
        for (int k = 0; k < HID; ++k)
            acc = __builtin_fmaf(W_fc[j * HID + k], th_s[g * HID + k], acc);
        out[(size_t)b * 5 + j] = acc;
    }
}

extern "C" void kernel_launch(void* const* d_in, const int* in_sizes, int n_in,
                              void* d_out, int out_size, void* d_ws, size_t ws_size,
                              hipStream_t stream) {
    const float* x    = (const float*)d_in[0];
    const float* W_ih = (const float*)d_in[1];
    const float* W_hh = (const float*)d_in[2];
    const float* b_ih = (const float*)d_in[3];
    const float* b_hh = (const float*)d_in[4];
    const float* W_fc = (const float*)d_in[5];
    const float* b_fc = (const float*)d_in[6];
    float* out = (float*)d_out;

    const int B = in_sizes[0] / TLEN;  // 4096
    gru_fused_kernel<<<dim3(B / 4), dim3(64), 0, stream>>>(
        x, W_ih, W_hh, b_ih, b_hh, W_fc, b_fc, out);
}

// Round 6
// 145.448 us; speedup vs baseline: 1.0629x; 1.0629x over previous
//
#include <hip/hip_runtime.h>

#define HID 16
#define TLEN 1024

typedef float v2f __attribute__((ext_vector_type(2)));
typedef float v4f __attribute__((ext_vector_type(4)));

__device__ __forceinline__ float fast_exp2(float a) { return __builtin_amdgcn_exp2f(a); }
__device__ __forceinline__ float fast_rcp(float a)  { return __builtin_amdgcn_rcpf(a); }

// tanh(a) = 1 - 2/(exp2(2a*log2e)+1)  (epilogue only, unscaled input)
__device__ __forceinline__ float fast_tanh(float a) {
    return __builtin_fmaf(-2.0f, fast_rcp(1.0f + fast_exp2(a * 2.8853900817779268f)), 1.0f);
}

// One lane per (sequence, hidden unit j). 64-thread blocks = 1 wave = 4 sequences.
// grid = B/4 = 1024 waves -> 1 wave per SIMD across 256 CUs (occupancy is
// structurally capped at 1 wave/SIMD; VGPR count is free up to ~256, all gains
// must come from per-step issue cycles on the serial h->h chain).
__global__ __launch_bounds__(64, 1) void gru_fused_kernel(
    const float* __restrict__ x,     // [B, T, 1]
    const float* __restrict__ W_ih,  // [48, 1]
    const float* __restrict__ W_hh,  // [48, 16]
    const float* __restrict__ b_ih,  // [48]
    const float* __restrict__ b_hh,  // [48]
    const float* __restrict__ W_fc,  // [5, 16]
    const float* __restrict__ b_fc,  // [5]
    float* __restrict__ out)         // [B, 5]
{
    const int lane = threadIdx.x;      // 0..63
    const int j    = lane & 15;        // hidden unit
    const int g    = lane >> 4;        // sequence-within-wave (0..3)
    const int b    = blockIdx.x * 4 + g;

    const float NEG_LOG2E = -1.4426950408889634f;  // sigmoid: rcp(1+exp2(-a*log2e))
    const float TWO_LOG2E =  2.8853900817779268f;  // tanh:    1-2*rcp(1+exp2(2a*log2e))

    // Per-lane weight PAIRS for the ror-form matvec (HW-verified in R4):
    // ror16<r>(h) at lane j yields h[(j-r)&15], pair p covers r = 2p, 2p+1:
    //   wrp[p] = { W[j][(j-2p)&15], W[j][(j-2p-1)&15] }  (pre-scaled for exp2)
    v2f wrp[8], wzp[8], wnp[8];
    #pragma unroll
    for (int p = 0; p < 8; ++p) {
        const int k0 = (j - 2 * p)     & 15;
        const int k1 = (j - 2 * p - 1) & 15;
        wrp[p] = v2f{ W_hh[(j     ) * HID + k0], W_hh[(j     ) * HID + k1] } * NEG_LOG2E;
        wzp[p] = v2f{ W_hh[(j + 16) * HID + k0], W_hh[(j + 16) * HID + k1] } * NEG_LOG2E;
        wnp[p] = v2f{ W_hh[(j + 32) * HID + k0], W_hh[(j + 32) * HID + k1] } * TWO_LOG2E;
    }
    const float wih_r = W_ih[j]      * NEG_LOG2E;
    const float wih_z = W_ih[j + 16] * NEG_LOG2E;
    const float wih_n = W_ih[j + 32] * TWO_LOG2E;
    const float br  = (b_ih[j]      + b_hh[j])      * NEG_LOG2E;
    const float bz  = (b_ih[j + 16] + b_hh[j + 16]) * NEG_LOG2E;
    const float bnx = b_ih[j + 32] * TWO_LOG2E;    // input-side n bias
    const float bnh = b_hh[j + 32] * TWO_LOG2E;    // hidden-side n bias (inside r*)

    const float* __restrict__ xb = x + (size_t)b * TLEN;

    float h = 0.0f;
    // current chunk's 16 x values, full copy per lane (same cachelines per group)
    v4f xc0 = *(const v4f*)(xb +  0);
    v4f xc1 = *(const v4f*)(xb +  4);
    v4f xc2 = *(const v4f*)(xb +  8);
    v4f xc3 = *(const v4f*)(xb + 12);

    for (int t0 = 0; t0 < TLEN; t0 += 16) {
        // prefetch next chunk (independent of the recurrence)
        v4f xn0 = {0,0,0,0}, xn1 = {0,0,0,0}, xn2 = {0,0,0,0}, xn3 = {0,0,0,0};
        if (t0 + 16 < TLEN) {
            xn0 = *(const v4f*)(xb + t0 + 16);
            xn1 = *(const v4f*)(xb + t0 + 20);
            xn2 = *(const v4f*)(xb + t0 + 24);
            xn3 = *(const v4f*)(xb + t0 + 28);
        }

        const v4f xcs[4] = { xc0, xc1, xc2, xc3 };
        #pragma unroll
        for (int i = 0; i < 16; ++i) {
            const float xt = xcs[i >> 2][i & 3];   // compile-time indices

            // input-gate terms (off the critical path)
            const float rx = __builtin_fmaf(xt, wih_r, br);
            const float zx = __builtin_fmaf(xt, wih_z, bz);
            const float nx = __builtin_fmaf(xt, wih_n, bnx);

            // ---- matvec: 15 DPP rotations of h written straight into the
            //      clobbered pair block v[40:55] (zero packing movs), then
            //      24 guaranteed v_pk_mul/pk_fma_f32 in 3 round-robin chains.
            //      dR/dZ/dN = packed partial dots; .x = even r, .y = odd r. ----
            v2f dR, dZ, dN;
            asm ("v_mov_b32 v40, %[h]\n\t"
                 "s_nop 1\n\t"   // VALU-write -> DPP-read wait states on h
                 "v_mov_b32_dpp v41, %[h] row_ror:1  row_mask:0xf bank_mask:0xf\n\t"
                 "v_mov_b32_dpp v42, %[h] row_ror:2  row_mask:0xf bank_mask:0xf\n\t"
                 "v_mov_b32_dpp v43, %[h] row_ror:3  row_mask:0xf bank_mask:0xf\n\t"
                 "v_mov_b32_dpp v44, %[h] row_ror:4  row_mask:0xf bank_mask:0xf\n\t"
                 "v_mov_b32_dpp v45, %[h] row_ror:5  row_mask:0xf bank_mask:0xf\n\t"
                 "v_mov_b32_dpp v46, %[h] row_ror:6  row_mask:0xf bank_mask:0xf\n\t"
                 "v_mov_b32_dpp v47, %[h] row_ror:7  row_mask:0xf bank_mask:0xf\n\t"
                 "v_mov_b32_dpp v48, %[h] row_ror:8  row_mask:0xf bank_mask:0xf\n\t"
                 "v_mov_b32_dpp v49, %[h] row_ror:9  row_mask:0xf bank_mask:0xf\n\t"
                 "v_mov_b32_dpp v50, %[h] row_ror:10 row_mask:0xf bank_mask:0xf\n\t"
                 "v_mov_b32_dpp v51, %[h] row_ror:11 row_mask:0xf bank_mask:0xf\n\t"
                 "v_mov_b32_dpp v52, %[h] row_ror:12 row_mask:0xf bank_mask:0xf\n\t"
                 "v_mov_b32_dpp v53, %[h] row_ror:13 row_mask:0xf bank_mask:0xf\n\t"
                 "v_mov_b32_dpp v54, %[h] row_ror:14 row_mask:0xf bank_mask:0xf\n\t"
                 "v_mov_b32_dpp v55, %[h] row_ror:15 row_mask:0xf bank_mask:0xf\n\t"
                 "v_pk_mul_f32 %[dr], %[wr0], v[40:41]\n\t"
                 "v_pk_mul_f32 %[dz], %[wz0], v[40:41]\n\t"
                 "v_pk_mul_f32 %[dn], %[wn0], v[40:41]\n\t"
                 "v_pk_fma_f32 %[dr], %[wr1], v[42:43], %[dr]\n\t"
                 "v_pk_fma_f32 %[dz], %[wz1], v[42:43], %[dz]\n\t"
                 "v_pk_fma_f32 %[dn], %[wn1], v[42:43], %[dn]\n\t"
                 "v_pk_fma_f32 %[dr], %[wr2], v[44:45], %[dr]\n\t"
                 "v_pk_fma_f32 %[dz], %[wz2], v[44:45], %[dz]\n\t"
                 "v_pk_fma_f32 %[dn], %[wn2], v[44:45], %[dn]\n\t"
                 "v_pk_fma_f32 %[dr], %[wr3], v[46:47], %[dr]\n\t"
                 "v_pk_fma_f32 %[dz], %[wz3], v[46:47], %[dz]\n\t"
                 "v_pk_fma_f32 %[dn], %[wn3], v[46:47], %[dn]\n\t"
                 "v_pk_fma_f32 %[dr], %[wr4], v[48:49], %[dr]\n\t"
                 "v_pk_fma_f32 %[dz], %[wz4], v[48:49], %[dz]\n\t"
                 "v_pk_fma_f32 %[dn], %[wn4], v[48:49], %[dn]\n\t"
                 "v_pk_fma_f32 %[dr], %[wr5], v[50:51], %[dr]\n\t"
                 "v_pk_fma_f32 %[dz], %[wz5], v[50:51], %[dz]\n\t"
                 "v_pk_fma_f32 %[dn], %[wn5], v[50:51], %[dn]\n\t"
                 "v_pk_fma_f32 %[dr], %[wr6], v[52:53], %[dr]\n\t"
                 "v_pk_fma_f32 %[dz], %[wz6], v[52:53], %[dz]\n\t"
                 "v_pk_fma_f32 %[dn], %[wn6], v[52:53], %[dn]\n\t"
                 "v_pk_fma_f32 %[dr], %[wr7], v[54:55], %[dr]\n\t"
                 "v_pk_fma_f32 %[dz], %[wz7], v[54:55], %[dz]\n\t"
                 "v_pk_fma_f32 %[dn], %[wn7], v[54:55], %[dn]\n\t"
                 : [dr]"=&v"(dR), [dz]"=&v"(dZ), [dn]"=&v"(dN)
                 : [h]"v"(h),
                   [wr0]"v"(wrp[0]), [wz0]"v"(wzp[0]), [wn0]"v"(wnp[0]),
                   [wr1]"v"(wrp[1]), [wz1]"v"(wzp[1]), [wn1]"v"(wnp[1]),
                   [wr2]"v"(wrp[2]), [wz2]"v"(wzp[2]), [wn2]"v"(wnp[2]),
                   [wr3]"v"(wrp[3]), [wz3]"v"(wzp[3]), [wn3]"v"(wnp[3]),
                   [wr4]"v"(wrp[4]), [wz4]"v"(wzp[4]), [wn4]"v"(wnp[4]),
                   [wr5]"v"(wrp[5]), [wz5]"v"(wzp[5]), [wn5]"v"(wnp[5]),
                   [wr6]"v"(wrp[6]), [wz6]"v"(wzp[6]), [wn6]"v"(wnp[6]),
                   [wr7]"v"(wrp[7]), [wz7]"v"(wzp[7]), [wn7]"v"(wnp[7])
                 : "v40","v41","v42","v43","v44","v45","v46","v47",
                   "v48","v49","v50","v51","v52","v53","v54","v55");

            const float ar = (dR.x + dR.y) + rx;
            const float az = (dZ.x + dZ.y) + zx;
            const float an = (dN.x + dN.y) + bnh;

            // activations (weights pre-scaled: no mul before exp2)
            const float r_ = fast_rcp(1.0f + fast_exp2(ar));
            const float z_ = fast_rcp(1.0f + fast_exp2(az));
            const float s_ = __builtin_fmaf(r_, an, nx);
            const float n_ = __builtin_fmaf(-2.0f, fast_rcp(1.0f + fast_exp2(s_)), 1.0f);

            // h = (1-z)*n + z*h
            h = __builtin_fmaf(z_, h - n_, n_);
        }

        xc0 = xn0; xc1 = xn1; xc2 = xn2; xc3 = xn3;
    }

    // --- epilogue: out[b, c] = sum_j tanh(h_j) * W_fc[c, j] + b_fc[c] ---
    __shared__ float th_s[64];
    th_s[lane] = fast_tanh(h);
    __syncthreads();

    if (j < 5) {
        float acc = b_fc[j];
        #pragma unroll
        for (int k = 0; k < HID; ++k)
            acc = __builtin_fmaf(W_fc[j * HID + k], th_s[g * HID + k], acc);
        out[(size_t)b * 5 + j] = acc;
    }
}

extern "C" void kernel_launch(void* const* d_in, const int* in_sizes, int n_in,
                              void* d_out, int out_size, void* d_ws, size_t ws_size,
                              hipStream_t stream) {
    const float* x    = (const float*)d_in[0];
    const float* W_ih = (const float*)d_in[1];
    const float* W_hh = (const float*)d_in[2];
    const float* b_ih = (const float*)d_in[3];
    const float* b_hh = (const float*)d_in[4];
    const float* W_fc = (const float*)d_in[5];
    const float* b_fc = (const float*)d_in[6];
    float* out = (float*)d_out;

    const int B = in_sizes[0] / TLEN;  // 4096
    gru_fused_kernel<<<dim3(B / 4), dim3(64), 0, stream>>>(
        x, W_ih, W_hh, b_ih, b_hh, W_fc, b_fc, out);
}

// Round 7
// 114.614 us; speedup vs baseline: 1.3489x; 1.2690x over previous
//
#include <hip/hip_runtime.h>

#define HID 16
#define TLEN 1024

typedef float v4f __attribute__((ext_vector_type(4)));
typedef _Float16 half_t;
typedef _Float16 v2h __attribute__((ext_vector_type(2)));

__device__ __forceinline__ float fast_exp2(float a) { return __builtin_amdgcn_exp2f(a); }
__device__ __forceinline__ float fast_rcp(float a)  { return __builtin_amdgcn_rcpf(a); }

// tanh(a) = 1 - 2/(exp2(2a*log2e)+1)  (epilogue only, unscaled input)
__device__ __forceinline__ float fast_tanh(float a) {
    return __builtin_fmaf(-2.0f, fast_rcp(1.0f + fast_exp2(a * 2.8853900817779268f)), 1.0f);
}

// DPP row_ror:R within 16-lane rows, HW-verified (R4/R6): dst[i] = src[(i-R)&15].
template<int R>
__device__ __forceinline__ float ror16f(float v) {
    return __builtin_bit_cast(float,
        __builtin_amdgcn_update_dpp(0, __builtin_bit_cast(int, v),
                                    0x120 + R, 0xF, 0xF, true));
}
template<int R>
__device__ __forceinline__ int ror16i(int v) {
    return __builtin_amdgcn_update_dpp(0, v, 0x120 + R, 0xF, 0xF, true);
}

// f16 packed dot with f32 accumulate: d = a.x*b.x + a.y*b.y + c  (v_dot2_f32_f16)
__device__ __forceinline__ float dot2(v2h a, v2h b, float c) {
#if __has_builtin(__builtin_amdgcn_fdot2)
    return __builtin_amdgcn_fdot2(a, b, c, false);
#else
    return __builtin_fmaf((float)a.y, (float)b.y,
           __builtin_fmaf((float)a.x, (float)b.x, c));
#endif
}

// One lane per (sequence, hidden unit j). 64-thread blocks = 1 wave = 4 sequences.
// grid = B/4 = 1024 waves -> 1 wave per SIMD across 256 CUs (occupancy is
// structurally capped at 1 wave/SIMD; all gains come from per-step issue
// cycles on the serial h->h chain).
__global__ __launch_bounds__(64, 1) void gru_fused_kernel(
    const float* __restrict__ x,     // [B, T, 1]
    const float* __restrict__ W_ih,  // [48, 1]
    const float* __restrict__ W_hh,  // [48, 16]
    const float* __restrict__ b_ih,  // [48]
    const float* __restrict__ b_hh,  // [48]
    const float* __restrict__ W_fc,  // [5, 16]
    const float* __restrict__ b_fc,  // [5]
    float* __restrict__ out)         // [B, 5]
{
    const int lane = threadIdx.x;      // 0..63
    const int j    = lane & 15;        // hidden unit
    const int g    = lane >> 4;        // sequence-within-wave (0..3)
    const int b    = blockIdx.x * 4 + g;

    const float NEG_LOG2E = -1.4426950408889634f;  // sigmoid: rcp(1+exp2(-a*log2e))
    const float TWO_LOG2E =  2.8853900817779268f;  // tanh:    1-2*rcp(1+exp2(2a*log2e))

    // Per-lane weight pairs (half2) for the ror-form matvec:
    //   pair p covers k0=(j-2p)&15, k1=(j-2p-1)&15, matching the h pair
    //   row_ror:2p of hp0 = {h_j, h_{j-1}}.
    // Quantize AFTER scaling (RNE via _Float16 cast); f32 h recurrence keeps
    // accumulation error out of the state.
    v2h wrp[8], wzp[8], wnp[8];
    #pragma unroll
    for (int p = 0; p < 8; ++p) {
        const int k0 = (j - 2 * p)     & 15;
        const int k1 = (j - 2 * p - 1) & 15;
        wrp[p] = v2h{ (half_t)(W_hh[(j     ) * HID + k0] * NEG_LOG2E),
                      (half_t)(W_hh[(j     ) * HID + k1] * NEG_LOG2E) };
        wzp[p] = v2h{ (half_t)(W_hh[(j + 16) * HID + k0] * NEG_LOG2E),
                      (half_t)(W_hh[(j + 16) * HID + k1] * NEG_LOG2E) };
        wnp[p] = v2h{ (half_t)(W_hh[(j + 32) * HID + k0] * TWO_LOG2E),
                      (half_t)(W_hh[(j + 32) * HID + k1] * TWO_LOG2E) };
    }
    const float wih_r = W_ih[j]      * NEG_LOG2E;
    const float wih_z = W_ih[j + 16] * NEG_LOG2E;
    const float wih_n = W_ih[j + 32] * TWO_LOG2E;
    const float br  = (b_ih[j]      + b_hh[j])      * NEG_LOG2E;
    const float bz  = (b_ih[j + 16] + b_hh[j + 16]) * NEG_LOG2E;
    const float bnx = b_ih[j + 32] * TWO_LOG2E;    // input-side n bias
    const float bnh = b_hh[j + 32] * TWO_LOG2E;    // hidden-side n bias (inside r*)

    const float* __restrict__ xb = x + (size_t)b * TLEN;

    float h = 0.0f;
    // current chunk's 16 x values, full copy per lane (same cachelines per group)
    v4f xc0 = *(const v4f*)(xb +  0);
    v4f xc1 = *(const v4f*)(xb +  4);
    v4f xc2 = *(const v4f*)(xb +  8);
    v4f xc3 = *(const v4f*)(xb + 12);

    for (int t0 = 0; t0 < TLEN; t0 += 16) {
        // prefetch next chunk (independent of the recurrence)
        v4f xn0 = {0,0,0,0}, xn1 = {0,0,0,0}, xn2 = {0,0,0,0}, xn3 = {0,0,0,0};
        if (t0 + 16 < TLEN) {
            xn0 = *(const v4f*)(xb + t0 + 16);
            xn1 = *(const v4f*)(xb + t0 + 20);
            xn2 = *(const v4f*)(xb + t0 + 24);
            xn3 = *(const v4f*)(xb + t0 + 28);
        }

        const v4f xcs[4] = { xc0, xc1, xc2, xc3 };
        #pragma unroll
        for (int i = 0; i < 16; ++i) {
            const float xt = xcs[i >> 2][i & 3];   // compile-time indices

            // input-gate terms (independent of h -> off the critical path)
            const float rx = __builtin_fmaf(xt, wih_r, br);
            const float zx = __builtin_fmaf(xt, wih_z, bz);
            const float nx = __builtin_fmaf(xt, wih_n, bnx);

            // ---- build the 8 rotated f16 h-pairs: 1 f32 DPP + pack + 7 packed DPPs ----
            const float hm1 = ror16f<1>(h);                 // h_{j-1}
            v2h hpv; hpv.x = (half_t)h; hpv.y = (half_t)hm1;
            const int hp0 = __builtin_bit_cast(int, hpv);   // {h_j, h_{j-1}}
            const int hp1 = ror16i< 2>(hp0);
            const int hp2 = ror16i< 4>(hp0);
            const int hp3 = ror16i< 6>(hp0);
            const int hp4 = ror16i< 8>(hp0);
            const int hp5 = ror16i<10>(hp0);
            const int hp6 = ror16i<12>(hp0);
            const int hp7 = ror16i<14>(hp0);
            const v2h h2_0 = __builtin_bit_cast(v2h, hp0);
            const v2h h2_1 = __builtin_bit_cast(v2h, hp1);
            const v2h h2_2 = __builtin_bit_cast(v2h, hp2);
            const v2h h2_3 = __builtin_bit_cast(v2h, hp3);
            const v2h h2_4 = __builtin_bit_cast(v2h, hp4);
            const v2h h2_5 = __builtin_bit_cast(v2h, hp5);
            const v2h h2_6 = __builtin_bit_cast(v2h, hp6);
            const v2h h2_7 = __builtin_bit_cast(v2h, hp7);

            // ---- 24 x v_dot2_f32_f16, 3 round-robin accumulator chains ----
            float ar = rx, az = zx, an = bnh;
            ar = dot2(wrp[0], h2_0, ar);
            az = dot2(wzp[0], h2_0, az);
            an = dot2(wnp[0], h2_0, an);
            ar = dot2(wrp[1], h2_1, ar);
            az = dot2(wzp[1], h2_1, az);
            an = dot2(wnp[1], h2_1, an);
            ar = dot2(wrp[2], h2_2, ar);
            az = dot2(wzp[2], h2_2, az);
            an = dot2(wnp[2], h2_2, an);
            ar = dot2(wrp[3], h2_3, ar);
            az = dot2(wzp[3], h2_3, az);
            an = dot2(wnp[3], h2_3, an);
            ar = dot2(wrp[4], h2_4, ar);
            az = dot2(wzp[4], h2_4, az);
            an = dot2(wnp[4], h2_4, an);
            ar = dot2(wrp[5], h2_5, ar);
            az = dot2(wzp[5], h2_5, az);
            an = dot2(wnp[5], h2_5, an);
            ar = dot2(wrp[6], h2_6, ar);
            az = dot2(wzp[6], h2_6, az);
            an = dot2(wnp[6], h2_6, an);
            ar = dot2(wrp[7], h2_7, ar);
            az = dot2(wzp[7], h2_7, az);
            an = dot2(wnp[7], h2_7, an);

            // activations (weights pre-scaled: no mul before exp2)
            const float r_ = fast_rcp(1.0f + fast_exp2(ar));
            const float z_ = fast_rcp(1.0f + fast_exp2(az));
            const float s_ = __builtin_fmaf(r_, an, nx);
            const float n_ = __builtin_fmaf(-2.0f, fast_rcp(1.0f + fast_exp2(s_)), 1.0f);

            // h = (1-z)*n + z*h
            h = __builtin_fmaf(z_, h - n_, n_);
        }

        xc0 = xn0; xc1 = xn1; xc2 = xn2; xc3 = xn3;
    }

    // --- epilogue: out[b, c] = sum_j tanh(h_j) * W_fc[c, j] + b_fc[c] ---
    __shared__ float th_s[64];
    th_s[lane] = fast_tanh(h);
    __syncthreads();

    if (j < 5) {
        float acc = b_fc[j];
        #pragma unroll
        for (int k = 0; k < HID; ++k)
            acc = __builtin_fmaf(W_fc[j * HID + k], th_s[g * HID + k], acc);
        out[(size_t)b * 5 + j] = acc;
    }
}

extern "C" void kernel_launch(void* const* d_in, const int* in_sizes, int n_in,
                              void* d_out, int out_size, void* d_ws, size_t ws_size,
                              hipStream_t stream) {
    const float* x    = (const float*)d_in[0];
    const float* W_ih = (const float*)d_in[1];
    const float* W_hh = (const float*)d_in[2];
    const float* b_ih = (const float*)d_in[3];
    const float* b_hh = (const float*)d_in[4];
    const float* W_fc = (const float*)d_in[5];
    const float* b_fc = (const float*)d_in[6];
    float* out = (float*)d_out;

    const int B = in_sizes[0] / TLEN;  // 4096
    gru_fused_kernel<<<dim3(B / 4), dim3(64), 0, stream>>>(
        x, W_ih, W_hh, b_ih, b_hh, W_fc, b_fc, out);
}